// Round 8
// baseline (364.278 us; speedup 1.0000x reference)
//
#include <hip/hip_runtime.h>
#include <hip/hip_bf16.h>
#include <stdint.h>

typedef __attribute__((ext_vector_type(8))) short short8;
typedef __attribute__((ext_vector_type(8))) unsigned short ushort8;
typedef __attribute__((ext_vector_type(4))) unsigned short ushort4v;
typedef __attribute__((ext_vector_type(4))) float f32x4;
typedef __attribute__((ext_vector_type(16))) float f32x16;

#define B_ 8
#define N_ 4096
#define C_ 256
#define D_ 32
#define LOG2E 1.44269504088896f

__device__ inline unsigned short f2bf(float f) {
  union { float f; unsigned u; } v; v.f = f;
  unsigned r = v.u + 0x7fffu + ((v.u >> 16) & 1u);
  return (unsigned short)(r >> 16);
}
__device__ inline float bf2f(unsigned short u) {
  return __uint_as_float(((unsigned)u) << 16);
}
__device__ inline float exp2_fast(float x) {
  float r; asm("v_exp_f32 %0, %1" : "=v"(r) : "v"(x)); return r;
}
__device__ inline unsigned cvt_pk_bf16(float lo, float hi) {
  unsigned r; asm("v_cvt_pk_bf16_f32 %0, %1, %2" : "=v"(r) : "v"(lo), "v"(hi)); return r;
}
// a <- [a.l0-31 | b.l0-31], b <- [a.l32-63 | b.l32-63]
__device__ inline void permlane32_swap(unsigned& a, unsigned& b) {
  asm volatile("v_permlane32_swap_b32 %0, %1" : "+v"(a), "+v"(b));
}
__device__ inline void gll16(const unsigned short* src, void* lds) {
  __builtin_amdgcn_global_load_lds((const __attribute__((address_space(1))) void*)src,
                                   (__attribute__((address_space(3))) void*)lds, 16, 0, 0);
}

// ---------------- kernel 0a: weight casts ----------------
// wcomb[320][256]: rows 0-31 w_q^T*log2e | 32-63 w_k^T | rows 64-319 filled by prep2.
__global__ __launch_bounds__(256) void prep_kernel(const float* __restrict__ wq,
                                                   const float* __restrict__ wk,
                                                   const float* __restrict__ wo,
                                                   const float* __restrict__ wv,
                                                   unsigned short* __restrict__ wcomb,
                                                   unsigned short* __restrict__ wv_b,
                                                   unsigned short* __restrict__ woT_b) {
  int i = blockIdx.x * 256 + threadIdx.x;  // total 147456
  if (i < 16384) {
    int row = i >> 8, kk = i & 255;
    float v = (row < 32) ? wq[kk * 32 + row] * LOG2E : wk[kk * 32 + (row - 32)];
    wcomb[i] = f2bf(v);
  } else if (i < 81920) {
    int j = i - 16384;
    wv_b[j] = f2bf(wv[j]);
  } else {
    int j = i - 81920;  // woT_b[e2][e] = wo[e][e2]
    int e2 = j >> 8, e = j & 255;
    woT_b[j] = f2bf(wo[e * 256 + e2]);
  }
}

// ---------------- kernel 0b: Wvo^T = Wo^T . Wv^T  (256x256, K=256) ----------------
__global__ __launch_bounds__(256) void prep2_kernel(const unsigned short* __restrict__ woT_b,
                                                    const unsigned short* __restrict__ wv_b,
                                                    unsigned short* __restrict__ wcomb) {
  const int lane = threadIdx.x & 63, w = threadIdx.x >> 6;
  const int g = lane >> 4, li = lane & 15;
  const int m0 = blockIdx.x * 64 + w * 16;
  const unsigned short* arow = woT_b + (size_t)(m0 + li) * 256 + (g << 3);
  const unsigned short* brow = wv_b + (size_t)li * 256 + (g << 3);
  f32x4 acc[16] = {};
  for (int kk = 0; kk < 256; kk += 32) {
    short8 a = *reinterpret_cast<const short8*>(arow + kk);
#pragma unroll
    for (int ct = 0; ct < 16; ++ct) {
      short8 bb = *reinterpret_cast<const short8*>(brow + (size_t)ct * 16 * 256 + kk);
      acc[ct] = __builtin_amdgcn_mfma_f32_16x16x32_bf16(a, bb, acc[ct], 0, 0, 0);
    }
  }
#pragma unroll
  for (int ct = 0; ct < 16; ++ct)
#pragma unroll
    for (int r = 0; r < 4; ++r)
      wcomb[(size_t)(64 + m0 + (g << 2) + r) * 256 + ct * 16 + li] = f2bf(acc[ct][r]);
}

// ---------------- kernel 1: fused QKVW projection (x read once) ----------------
__global__ __launch_bounds__(256, 4) void qkv_kernel(const float* __restrict__ x,
                                                     const unsigned short* __restrict__ wcomb,
                                                     unsigned short* __restrict__ q,
                                                     unsigned short* __restrict__ k,
                                                     unsigned short* __restrict__ vwT) {
  const int lane = threadIdx.x & 63, w = threadIdx.x >> 6;
  const int bx = blockIdx.x;
  const int g = lane >> 4, li = lane & 15;
  const int mt = bx * 64 + w * 16;
  const float* xrow = x + (size_t)(mt + li) * 256 + (g << 3);
  const unsigned short* wrow = wcomb + (size_t)li * 256 + (g << 3);
  f32x4 acc[20] = {};
  for (int kk = 0; kk < 256; kk += 32) {
    f32x4 a0 = *reinterpret_cast<const f32x4*>(xrow + kk);
    f32x4 a1 = *reinterpret_cast<const f32x4*>(xrow + kk + 4);
    union { unsigned u[4]; short8 v; } A;
    A.u[0] = cvt_pk_bf16(a0[0], a0[1]);
    A.u[1] = cvt_pk_bf16(a0[2], a0[3]);
    A.u[2] = cvt_pk_bf16(a1[0], a1[1]);
    A.u[3] = cvt_pk_bf16(a1[2], a1[3]);
    short8 a = A.v;
#pragma unroll
    for (int ct = 0; ct < 20; ++ct) {
      short8 bb = *reinterpret_cast<const short8*>(wrow + (size_t)ct * 16 * 256 + kk);
      acc[ct] = __builtin_amdgcn_mfma_f32_16x16x32_bf16(a, bb, acc[ct], 0, 0, 0);
    }
  }
  const int bb_ = bx >> 6;
  const int nloc = (bx & 63) * 64 + w * 16 + (g << 2);
#pragma unroll
  for (int ct = 0; ct < 4; ++ct) {
    int col = ct * 16 + li;
    unsigned short* dst = (ct < 2) ? q : k;
    int cc = (ct < 2) ? col : col - 32;
#pragma unroll
    for (int r = 0; r < 4; ++r)
      dst[((size_t)bb_ * N_ + nloc + r) * D_ + cc] = f2bf(acc[ct][r]);
  }
#pragma unroll
  for (int ct = 4; ct < 20; ++ct) {
    int vcol = (ct - 4) * 16 + li;
    union { unsigned u[2]; ushort4v v; } P;
    P.u[0] = cvt_pk_bf16(acc[ct][0], acc[ct][1]);
    P.u[1] = cvt_pk_bf16(acc[ct][2], acc[ct][3]);
    *reinterpret_cast<ushort4v*>(&vwT[((size_t)bb_ * C_ + vcol) * N_ + nloc]) = P.v;
  }
}

// ---------------- kernel 2: flash attention (8-wave blocks, K in regs) ----------------
// grid 512 x 512 threads. blk: b = blk&7 (XCD pin), kvh = (blk>>3)&1, qt = blk>>4.
// Block tile 128q x 256c over 2048 kv (64 chunks of 32). 8 waves: qs = w>>1, ch = w&1;
// wave = 32q x 128c. V quad-buffered in LDS (4x16KB), staged 2 chunks ahead via
// global_load_lds; K chunk loaded direct from L2 into a double-buffered register
// set. Uniform 4 vm-loads per chunk per wave -> steady-state s_waitcnt vmcnt(4),
// drained to 0 only at the last chunk. One s_barrier per chunk couples the block.
// P stays in registers (swapped S^T=K.Q^T, fixed m=0, q pre-scaled log2e); the
// output projection is folded into vwT. Writes unnormalized bf16 O partial + f32
// lsum partial per kvh; merged by merge_kernel.
__global__ __launch_bounds__(512, 4) void flash_kernel(const unsigned short* __restrict__ q,
                                                       const unsigned short* __restrict__ k,
                                                       const unsigned short* __restrict__ vwT,
                                                       unsigned short* __restrict__ opart,
                                                       float* __restrict__ lsumpart) {
  __shared__ __align__(16) char smem[65536];  // V 4 x 16KB
  const int tid = threadIdx.x;
  const int l = tid & 63, w_ = tid >> 6;
  const int qs = w_ >> 1, ch = w_ & 1;
  const int blk = blockIdx.x;
  const int b = blk & 7;
  const int kvh = (blk >> 3) & 1;
  const int qt = blk >> 4;  // 0..31
  const int h = l >> 5, l31 = l & 31;

  const unsigned short* kb_ = k + (size_t)b * N_ * D_;
  const unsigned short* vb_ = vwT + (size_t)b * C_ * N_;

  // Q B-frags: col q = l31, k-dim = ks*16 + 8h + j
  const int qpos = qt * 128 + qs * 32 + l31;
  const size_t qoff = ((size_t)b * N_ + qpos) * D_ + h * 8;
  const short8 qb0 = *reinterpret_cast<const short8*>(q + qoff);
  const short8 qb1 = *reinterpret_cast<const short8*>(q + qoff + 16);
  asm volatile("s_waitcnt vmcnt(0)" ::: "memory");  // clean vm counter before staging

  // V staging: wave stages rows w_*32..+31 as 2 gll16 granules (16 rows x 64B each);
  // lane -> (row = l>>2, 16B-pos = l&3); source pre-swizzled: pos p holds data
  // block p ^ ((row>>1)&3)  (key == (l>>3)&3 within a granule).
  const int stg_row = l >> 2;
  const int stg_bk = ((l & 3) ^ ((l >> 3) & 3)) << 3;  // elems
  const int kvbase = kvh * 2048;

#define STAGE(BUF, KV0)                                                           \
  {                                                                               \
    char* vd = smem + (BUF) * 16384 + w_ * 2048;                                  \
    gll16(vb_ + (size_t)(w_ * 32 + stg_row) * N_ + (KV0) + stg_bk, vd);           \
    gll16(vb_ + (size_t)(w_ * 32 + 16 + stg_row) * N_ + (KV0) + stg_bk, vd + 1024); \
  }

  // K A-frags direct from global (L2-resident): row kv = l31, d = 16s + 8h + j
  const unsigned short* kl = kb_ + 8 * h;
  short8 ka00, ka01, ka10, ka11;
#define KLOAD0(KV0)                                                                \
  {                                                                                \
    ka00 = *reinterpret_cast<const short8*>(kl + (size_t)((KV0) + l31) * D_);      \
    ka01 = *reinterpret_cast<const short8*>(kl + (size_t)((KV0) + l31) * D_ + 16); \
  }
#define KLOAD1(KV0)                                                                \
  {                                                                                \
    ka10 = *reinterpret_cast<const short8*>(kl + (size_t)((KV0) + l31) * D_);      \
    ka11 = *reinterpret_cast<const short8*>(kl + (size_t)((KV0) + l31) * D_ + 16); \
  }

  f32x16 o[4] = {};  // O^T (32c x 32q) per ct, c = ch*128 + ct*32 + ...
  float lsum = 0.f;
  const f32x16 z16 = {};

  STAGE(0, kvbase) KLOAD0(kvbase)
  __builtin_amdgcn_sched_barrier(0);  // keep chunk-0 loads older than chunk-1
  STAGE(1, kvbase + 32) KLOAD1(kvbase + 32)

#define ITER(I, BUF, KA0, KA1, KLOADM)                                                 \
  {                                                                                    \
    if ((I) < 63) { asm volatile("s_waitcnt vmcnt(4)" ::: "memory"); }                 \
    else          { asm volatile("s_waitcnt vmcnt(0)" ::: "memory"); }                 \
    __builtin_amdgcn_sched_barrier(0);                                                 \
    __builtin_amdgcn_s_barrier();                                                      \
    __builtin_amdgcn_sched_barrier(0);                                                 \
    if ((I) < 62) STAGE(((I) + 2) & 3, kvbase + ((I) + 2) * 32)                        \
    const char* Vb = smem + (BUF) * 16384;                                             \
    f32x16 s = __builtin_amdgcn_mfma_f32_32x32x16_bf16(KA0, qb0, z16, 0, 0, 0);        \
    s = __builtin_amdgcn_mfma_f32_32x32x16_bf16(KA1, qb1, s, 0, 0, 0);                 \
    if ((I) < 62) KLOADM(kvbase + ((I) + 2) * 32)                                      \
    float p[16];                                                                       \
    _Pragma("unroll") for (int r = 0; r < 16; ++r) p[r] = exp2_fast(s[r]);             \
    lsum += (((p[0] + p[1]) + (p[2] + p[3])) + ((p[4] + p[5]) + (p[6] + p[7]))) +      \
            (((p[8] + p[9]) + (p[10] + p[11])) + ((p[12] + p[13]) + (p[14] + p[15]))); \
    unsigned x0 = cvt_pk_bf16(p[0], p[1]),   y0 = cvt_pk_bf16(p[4], p[5]);             \
    unsigned x1 = cvt_pk_bf16(p[2], p[3]),   y1 = cvt_pk_bf16(p[6], p[7]);             \
    unsigned x2 = cvt_pk_bf16(p[8], p[9]),   y2 = cvt_pk_bf16(p[12], p[13]);           \
    unsigned x3 = cvt_pk_bf16(p[10], p[11]), y3 = cvt_pk_bf16(p[14], p[15]);           \
    permlane32_swap(x0, y0); permlane32_swap(x1, y1);                                  \
    permlane32_swap(x2, y2); permlane32_swap(x3, y3);                                  \
    union U { unsigned u[4]; short8 v; };                                              \
    U u0; u0.u[0] = x0; u0.u[1] = x1; u0.u[2] = y0; u0.u[3] = y1;                      \
    U u1; u1.u[0] = x2; u1.u[1] = x3; u1.u[2] = y2; u1.u[3] = y3;                      \
    __builtin_amdgcn_s_setprio(1);                                                     \
    _Pragma("unroll") for (int ct = 0; ct < 4; ++ct) {                                 \
      const int rl = ch * 128 + ct * 32 + l31;                                         \
      const int vkey = (rl >> 1) & 3;                                                  \
      short8 va0 = *reinterpret_cast<const short8*>(Vb + rl * 64 + (((0 + h) ^ vkey) << 4)); \
      short8 va1 = *reinterpret_cast<const short8*>(Vb + rl * 64 + (((2 + h) ^ vkey) << 4)); \
      o[ct] = __builtin_amdgcn_mfma_f32_32x32x16_bf16(va0, u0.v, o[ct], 0, 0, 0);      \
      o[ct] = __builtin_amdgcn_mfma_f32_32x32x16_bf16(va1, u1.v, o[ct], 0, 0, 0);      \
    }                                                                                  \
    __builtin_amdgcn_s_setprio(0);                                                     \
  }

  for (int i = 0; i < 64; i += 4) {
    ITER(i + 0, 0, ka00, ka01, KLOAD0)
    ITER(i + 1, 1, ka10, ka11, KLOAD1)
    ITER(i + 2, 2, ka00, ka01, KLOAD0)
    ITER(i + 3, 3, ka10, ka11, KLOAD1)
  }

  // ---- epilogue: unnormalized bf16 O partial + f32 lsum partial ----
  lsum += __shfl_xor(lsum, 32);
  unsigned short* op = opart + ((size_t)kvh * B_ + b) * (size_t)N_ * C_;
  const size_t rowoff = (size_t)qpos * C_ + ch * 128;
#pragma unroll
  for (int ct = 0; ct < 4; ++ct)
#pragma unroll
    for (int j = 0; j < 8; ++j) {
      const int c = ct * 32 + 2 * (j & 1) + 8 * (j >> 1) + 4 * h;
      unsigned wv = cvt_pk_bf16(o[ct][2 * j], o[ct][2 * j + 1]);
      *reinterpret_cast<unsigned*>(&op[rowoff + c]) = wv;
    }
  if (h == 0 && ch == 0)
    lsumpart[((size_t)kvh * B_ + b) * N_ + qpos] = lsum;
#undef ITER
#undef KLOAD0
#undef KLOAD1
#undef STAGE
}

// ---------------- kernel 3: merge kv-split partials + residual ----------------
// out = x + (O0 + O1) / (l0 + l1).  8192 blocks x 256 thr x one f32x4 group.
__global__ __launch_bounds__(256) void merge_kernel(const unsigned short* __restrict__ opart,
                                                    const float* __restrict__ lsumpart,
                                                    const float* __restrict__ x,
                                                    float* __restrict__ out) {
  const int i4 = blockIdx.x * 256 + threadIdx.x;  // f32x4 group, total 2097152
  const int m = i4 >> 6;                          // row (64 groups per 256-c row)
  const float inv = 1.0f / (lsumpart[m] + lsumpart[B_ * N_ + m]);
  ushort4v a0 = *reinterpret_cast<const ushort4v*>(opart + (size_t)i4 * 4);
  ushort4v a1 = *reinterpret_cast<const ushort4v*>(opart + (size_t)B_ * N_ * C_ + (size_t)i4 * 4);
  f32x4 xr = *reinterpret_cast<const f32x4*>(x + (size_t)i4 * 4);
  f32x4 t;
  t[0] = xr[0] + (bf2f(a0[0]) + bf2f(a1[0])) * inv;
  t[1] = xr[1] + (bf2f(a0[1]) + bf2f(a1[1])) * inv;
  t[2] = xr[2] + (bf2f(a0[2]) + bf2f(a1[2])) * inv;
  t[3] = xr[3] + (bf2f(a0[3]) + bf2f(a1[3])) * inv;
  *reinterpret_cast<f32x4*>(out + (size_t)i4 * 4) = t;
}

extern "C" void kernel_launch(void* const* d_in, const int* in_sizes, int n_in,
                              void* d_out, int out_size, void* d_ws, size_t ws_size,
                              hipStream_t stream) {
  const float* x  = (const float*)d_in[0];
  const float* wq = (const float*)d_in[1];
  const float* wk = (const float*)d_in[2];
  const float* wv = (const float*)d_in[3];
  const float* wo = (const float*)d_in[4];
  float* out = (float*)d_out;
  char* ws = (char*)d_ws;
  unsigned short* wcomb = (unsigned short*)(ws + 0);         // 163840 B
  unsigned short* wv_b  = (unsigned short*)(ws + 163840);    // 131072 B
  unsigned short* woT_b = (unsigned short*)(ws + 294912);    // 131072 B
  unsigned short* q     = (unsigned short*)(ws + 425984);    // 2 MB
  unsigned short* k     = (unsigned short*)(ws + 2523136);   // 2 MB
  unsigned short* vwT   = (unsigned short*)(ws + 4620288);   // 16 MB
  unsigned short* opart = (unsigned short*)(ws + 21397504);  // 32 MB (2 parts)
  float*          lsump = (float*)(ws + 54951936);           // 256 KB (total ~55.2 MB)

  prep_kernel<<<576, 256, 0, stream>>>(wq, wk, wo, wv, wcomb, wv_b, woT_b);
  prep2_kernel<<<4, 256, 0, stream>>>(woT_b, wv_b, wcomb);
  qkv_kernel<<<512, 256, 0, stream>>>(x, wcomb, q, k, vwT);
  flash_kernel<<<512, 512, 0, stream>>>(q, k, vwT, opart, lsump);
  merge_kernel<<<8192, 256, 0, stream>>>(opart, lsump, x, out);
}

// Round 9
// 173.302 us; speedup vs baseline: 2.1020x; 2.1020x over previous
//
#include <hip/hip_runtime.h>
#include <hip/hip_bf16.h>
#include <stdint.h>

typedef __attribute__((ext_vector_type(8))) short short8;
typedef __attribute__((ext_vector_type(8))) unsigned short ushort8;
typedef __attribute__((ext_vector_type(4))) unsigned short ushort4v;
typedef __attribute__((ext_vector_type(4))) float f32x4;
typedef __attribute__((ext_vector_type(16))) float f32x16;

#define B_ 8
#define N_ 4096
#define C_ 256
#define D_ 32
#define LOG2E 1.44269504088896f

__device__ inline unsigned short f2bf(float f) {
  union { float f; unsigned u; } v; v.f = f;
  unsigned r = v.u + 0x7fffu + ((v.u >> 16) & 1u);
  return (unsigned short)(r >> 16);
}
__device__ inline float bf2f(unsigned short u) {
  return __uint_as_float(((unsigned)u) << 16);
}
__device__ inline float exp2_fast(float x) {
  float r; asm("v_exp_f32 %0, %1" : "=v"(r) : "v"(x)); return r;
}
__device__ inline unsigned cvt_pk_bf16(float lo, float hi) {
  unsigned r; asm("v_cvt_pk_bf16_f32 %0, %1, %2" : "=v"(r) : "v"(lo), "v"(hi)); return r;
}
// a <- [a.l0-31 | b.l0-31], b <- [a.l32-63 | b.l32-63]
__device__ inline void permlane32_swap(unsigned& a, unsigned& b) {
  asm volatile("v_permlane32_swap_b32 %0, %1" : "+v"(a), "+v"(b));
}
__device__ inline void gll16(const unsigned short* src, void* lds) {
  __builtin_amdgcn_global_load_lds((const __attribute__((address_space(1))) void*)src,
                                   (__attribute__((address_space(3))) void*)lds, 16, 0, 0);
}

// ---------------- kernel 0a: weight casts ----------------
// wcomb[320][256]: rows 0-31 w_q^T*log2e | 32-63 w_k^T | rows 64-319 filled by prep2.
__global__ __launch_bounds__(256) void prep_kernel(const float* __restrict__ wq,
                                                   const float* __restrict__ wk,
                                                   const float* __restrict__ wo,
                                                   const float* __restrict__ wv,
                                                   unsigned short* __restrict__ wcomb,
                                                   unsigned short* __restrict__ wv_b,
                                                   unsigned short* __restrict__ woT_b) {
  int i = blockIdx.x * 256 + threadIdx.x;  // total 147456
  if (i < 16384) {
    int row = i >> 8, kk = i & 255;
    float v = (row < 32) ? wq[kk * 32 + row] * LOG2E : wk[kk * 32 + (row - 32)];
    wcomb[i] = f2bf(v);
  } else if (i < 81920) {
    int j = i - 16384;
    wv_b[j] = f2bf(wv[j]);
  } else {
    int j = i - 81920;  // woT_b[e2][e] = wo[e][e2]
    int e2 = j >> 8, e = j & 255;
    woT_b[j] = f2bf(wo[e * 256 + e2]);
  }
}

// ---------------- kernel 0b: Wvo^T = Wo^T . Wv^T  (256x256, K=256) ----------------
__global__ __launch_bounds__(256) void prep2_kernel(const unsigned short* __restrict__ woT_b,
                                                    const unsigned short* __restrict__ wv_b,
                                                    unsigned short* __restrict__ wcomb) {
  const int lane = threadIdx.x & 63, w = threadIdx.x >> 6;
  const int g = lane >> 4, li = lane & 15;
  const int m0 = blockIdx.x * 64 + w * 16;
  const unsigned short* arow = woT_b + (size_t)(m0 + li) * 256 + (g << 3);
  const unsigned short* brow = wv_b + (size_t)li * 256 + (g << 3);
  f32x4 acc[16] = {};
  for (int kk = 0; kk < 256; kk += 32) {
    short8 a = *reinterpret_cast<const short8*>(arow + kk);
#pragma unroll
    for (int ct = 0; ct < 16; ++ct) {
      short8 bb = *reinterpret_cast<const short8*>(brow + (size_t)ct * 16 * 256 + kk);
      acc[ct] = __builtin_amdgcn_mfma_f32_16x16x32_bf16(a, bb, acc[ct], 0, 0, 0);
    }
  }
#pragma unroll
  for (int ct = 0; ct < 16; ++ct)
#pragma unroll
    for (int r = 0; r < 4; ++r)
      wcomb[(size_t)(64 + m0 + (g << 2) + r) * 256 + ct * 16 + li] = f2bf(acc[ct][r]);
}

// ---------------- kernel 1: fused QKVW projection, W staged in LDS ----------------
// grid 512 x 256. Per block: 64 rows of x. W k-slices (20KB = 20 tiles of 16x32)
// triple-buffered in LDS, staged 2-ahead via gll16 (5/wave/step), counted vmcnt(5).
// All x loads hoisted to entry (issued BEFORE stages so their waits never drain
// the prefetch). 8 fully-unrolled k-steps (static xb[] indices).
__global__ __launch_bounds__(256, 2) void qkv_kernel(const float* __restrict__ x,
                                                     const unsigned short* __restrict__ wcomb,
                                                     unsigned short* __restrict__ q,
                                                     unsigned short* __restrict__ k,
                                                     unsigned short* __restrict__ vwT) {
  __shared__ __align__(16) char wls[61440];  // 3 x 20480
  const int tid = threadIdx.x;
  const int l = tid & 63, w = tid >> 6;
  const int bx = blockIdx.x;
  const int g = l >> 4, li = l & 15;
  const int mt = bx * 64 + w * 16;
  const float* xrow = x + (size_t)(mt + li) * 256 + (g << 3);

  // ---- issue all x loads first (oldest in vm queue) ----
  f32x4 xf[16];
#pragma unroll
  for (int s = 0; s < 8; ++s) {
    xf[2 * s]     = *reinterpret_cast<const f32x4*>(xrow + s * 32);
    xf[2 * s + 1] = *reinterpret_cast<const f32x4*>(xrow + s * 32 + 4);
  }
  __builtin_amdgcn_sched_barrier(0);  // keep x loads older than W stages

  // W staging: tile ct (16 rows x 32 k): lane -> (row = l>>2, 16B-pos = l&3);
  // source pre-swizzled: pos p holds k-chunk p ^ (row&3).
#define WSTAGE(BUF, S)                                                              \
  {                                                                                 \
    _Pragma("unroll") for (int t = 0; t < 5; ++t) {                                 \
      const int ct = w * 5 + t;                                                     \
      gll16(wcomb + (size_t)(ct * 16 + (l >> 2)) * 256 + (S) * 32 +                 \
                (((l & 3) ^ ((l >> 2) & 3)) << 3),                                  \
            wls + (BUF) * 20480 + ct * 1024);                                       \
    }                                                                               \
  }

  WSTAGE(0, 0)
  WSTAGE(1, 1)

  // convert x to bf16 A-frags (waits drain x loads only; stages are newer)
  short8 xb[8];
#pragma unroll
  for (int s = 0; s < 8; ++s) {
    union { unsigned u[4]; short8 v; } A;
    A.u[0] = cvt_pk_bf16(xf[2 * s][0], xf[2 * s][1]);
    A.u[1] = cvt_pk_bf16(xf[2 * s][2], xf[2 * s][3]);
    A.u[2] = cvt_pk_bf16(xf[2 * s + 1][0], xf[2 * s + 1][1]);
    A.u[3] = cvt_pk_bf16(xf[2 * s + 1][2], xf[2 * s + 1][3]);
    xb[s] = A.v;
  }

  f32x4 acc[20] = {};
  const int roff = li * 64 + ((g ^ (li & 3)) << 4);

#define QSTEP(S, BUF, WN, DOSTAGE)                                                  \
  {                                                                                 \
    asm volatile("s_waitcnt vmcnt(" WN ")" ::: "memory");                           \
    __builtin_amdgcn_sched_barrier(0);                                              \
    __builtin_amdgcn_s_barrier();                                                   \
    if (DOSTAGE) WSTAGE(((S) + 2) % 3, (S) + 2)                                     \
    const char* Wb = wls + (BUF) * 20480;                                           \
    _Pragma("unroll") for (int ct = 0; ct < 20; ++ct) {                             \
      short8 bb = *reinterpret_cast<const short8*>(Wb + ct * 1024 + roff);          \
      acc[ct] = __builtin_amdgcn_mfma_f32_16x16x32_bf16(xb[(S)], bb, acc[ct], 0, 0, 0); \
    }                                                                               \
  }

  QSTEP(0, 0, "5", true)
  QSTEP(1, 1, "5", true)
  QSTEP(2, 2, "5", true)
  QSTEP(3, 0, "5", true)
  QSTEP(4, 1, "5", true)
  QSTEP(5, 2, "5", true)
  QSTEP(6, 0, "5", false)
  QSTEP(7, 1, "0", false)

  const int bb_ = bx >> 6;
  const int nloc = (bx & 63) * 64 + w * 16 + (g << 2);
#pragma unroll
  for (int ct = 0; ct < 4; ++ct) {
    int col = ct * 16 + li;
    unsigned short* dst = (ct < 2) ? q : k;
    int cc = (ct < 2) ? col : col - 32;
#pragma unroll
    for (int r = 0; r < 4; ++r)
      dst[((size_t)bb_ * N_ + nloc + r) * D_ + cc] = f2bf(acc[ct][r]);
  }
#pragma unroll
  for (int ct = 4; ct < 20; ++ct) {
    int vcol = (ct - 4) * 16 + li;
    union { unsigned u[2]; ushort4v v; } P;
    P.u[0] = cvt_pk_bf16(acc[ct][0], acc[ct][1]);
    P.u[1] = cvt_pk_bf16(acc[ct][2], acc[ct][3]);
    *reinterpret_cast<ushort4v*>(&vwT[((size_t)bb_ * C_ + vcol) * N_ + nloc]) = P.v;
  }
#undef QSTEP
#undef WSTAGE
}

// ---------------- kernel 2: flash attention (r7 structure + kv-split, 3 blocks/CU) --
// grid 1024 x 256. blk: b = blk&7 (XCD pin), kvh = (blk>>3)&1, qt = blk>>4 (0..63).
// Block tile 64q x 256c over 2048 kv (64 chunks of 32). 4 waves: qs = w>>1, ch = w&1;
// wave = 32q x 128c (VGPR ~90, no spill at cap 170). V triple-buffered 3x16KB staged
// 2-ahead; K double-buffered 2x2KB staged 1-AHEAD and issued BEFORE the V stage so
// the steady-state wait is vmcnt(4) for every wave (outstanding-trace verified).
// LDS 53248 B -> 3 blocks/CU = 12 waves/CU. One s_barrier per chunk. P in registers
// (swapped S^T=K.Q^T, fixed m=0); output projection folded into vwT. Writes
// unnormalized bf16 O partial + f32 lsum partial per kvh; merged by merge_kernel.
__global__ __launch_bounds__(256, 3) void flash_kernel(const unsigned short* __restrict__ q,
                                                       const unsigned short* __restrict__ k,
                                                       const unsigned short* __restrict__ vwT,
                                                       unsigned short* __restrict__ opart,
                                                       float* __restrict__ lsumpart) {
  __shared__ __align__(16) char smem[53248];  // V 3x16384 @0 | K 2x2048 @49152
  const int tid = threadIdx.x;
  const int l = tid & 63, w_ = tid >> 6;
  const int qs = w_ >> 1, ch = w_ & 1;
  const int blk = blockIdx.x;
  const int b = blk & 7;
  const int kvh = (blk >> 3) & 1;
  const int qt = blk >> 4;  // 0..63
  const int h = l >> 5, l31 = l & 31;

  const unsigned short* kb_ = k + (size_t)b * N_ * D_;
  const unsigned short* vb_ = vwT + (size_t)b * C_ * N_;

  // Q B-frags: col q = l31, k-dim = ks*16 + 8h + j
  const int qpos = qt * 64 + qs * 32 + l31;
  const size_t qoff = ((size_t)b * N_ + qpos) * D_ + h * 8;
  const short8 qb0 = *reinterpret_cast<const short8*>(q + qoff);
  const short8 qb1 = *reinterpret_cast<const short8*>(q + qoff + 16);
  asm volatile("s_waitcnt vmcnt(0)" ::: "memory");  // clean vm counter before staging

  const int stg_row = l >> 2;
  const int stg_bk = ((l & 3) ^ ((l >> 3) & 3)) << 3;  // elems
  const int kvbase = kvh * 2048;

  // wave stages V rows w_*64..+63 (4 gll16); waves 0,1 stage 16 K rows each (1 gll16).
#define STAGE_V(BUF, KV0)                                                         \
  {                                                                               \
    char* vd = smem + (BUF) * 16384 + w_ * 4096;                                  \
    _Pragma("unroll") for (int t = 0; t < 4; ++t)                                 \
        gll16(vb_ + (size_t)(w_ * 64 + t * 16 + stg_row) * N_ + (KV0) + stg_bk,   \
              vd + t * 1024);                                                     \
  }
#define STAGE_K(BUF, KV0)                                                         \
  {                                                                               \
    if (w_ < 2)                                                                   \
      gll16(kb_ + (size_t)((KV0) + w_ * 16 + stg_row) * D_ + stg_bk,              \
            smem + 49152 + (BUF) * 2048 + w_ * 1024);                             \
  }

  f32x16 o[4] = {};  // O^T (32c x 32q) per ct, c range = ch*128 + ct*32
  float lsum = 0.f;
  const f32x16 z16 = {};

  // prologue order: V(0)x4, K(0), V(1)x4  -> first-iter vmcnt(4) drains V(0)+K(0)
  STAGE_V(0, kvbase)
  STAGE_K(0, kvbase)
  STAGE_V(1, kvbase + 32)

  int cur = 0, nxt = 2;
  for (int i = 0; i < 64; ++i) {
    if (i < 63) { asm volatile("s_waitcnt vmcnt(4)" ::: "memory"); }
    else        { asm volatile("s_waitcnt vmcnt(0)" ::: "memory"); }
    __builtin_amdgcn_sched_barrier(0);
    __builtin_amdgcn_s_barrier();  // chunk i landed; all waves done with prev reads
    // K 1-ahead FIRST (older than V(i+2) in vm queue), then V 2-ahead
    if (i < 63) STAGE_K((i + 1) & 1, kvbase + (i + 1) * 32)
    if (i < 62) STAGE_V(nxt, kvbase + (i + 2) * 32)
    const char* Vb = smem + cur * 16384;
    const char* Kb = smem + 49152 + (i & 1) * 2048;
    // ---- S^T[32kv][32q] = K . Q^T ----
    const int kkey = (l31 >> 1) & 3;
    short8 ka0 = *reinterpret_cast<const short8*>(Kb + l31 * 64 + (((0 + h) ^ kkey) << 4));
    short8 ka1 = *reinterpret_cast<const short8*>(Kb + l31 * 64 + (((2 + h) ^ kkey) << 4));
    f32x16 s = __builtin_amdgcn_mfma_f32_32x32x16_bf16(ka0, qb0, z16, 0, 0, 0);
    s = __builtin_amdgcn_mfma_f32_32x32x16_bf16(ka1, qb1, s, 0, 0, 0);
    float p[16];
#pragma unroll
    for (int r = 0; r < 16; ++r) p[r] = exp2_fast(s[r]);
    lsum += (((p[0] + p[1]) + (p[2] + p[3])) + ((p[4] + p[5]) + (p[6] + p[7]))) +
            (((p[8] + p[9]) + (p[10] + p[11])) + ((p[12] + p[13]) + (p[14] + p[15])));
    unsigned x0 = cvt_pk_bf16(p[0], p[1]),   y0 = cvt_pk_bf16(p[4], p[5]);
    unsigned x1 = cvt_pk_bf16(p[2], p[3]),   y1 = cvt_pk_bf16(p[6], p[7]);
    unsigned x2 = cvt_pk_bf16(p[8], p[9]),   y2 = cvt_pk_bf16(p[12], p[13]);
    unsigned x3 = cvt_pk_bf16(p[10], p[11]), y3 = cvt_pk_bf16(p[14], p[15]);
    permlane32_swap(x0, y0); permlane32_swap(x1, y1);
    permlane32_swap(x2, y2); permlane32_swap(x3, y3);
    union U { unsigned u[4]; short8 v; };
    U u0; u0.u[0] = x0; u0.u[1] = x1; u0.u[2] = y0; u0.u[3] = y1;  // kv 0-15
    U u1; u1.u[0] = x2; u1.u[1] = x3; u1.u[2] = y2; u1.u[3] = y3;  // kv 16-31
    // ---- PV: O^T[c][q] += V^T . P^T ----
    __builtin_amdgcn_s_setprio(1);
#pragma unroll
    for (int ct = 0; ct < 4; ++ct) {
      const int rl = ch * 128 + ct * 32 + l31;
      const int vkey = (rl >> 1) & 3;
      short8 va0 = *reinterpret_cast<const short8*>(Vb + rl * 64 + (((0 + h) ^ vkey) << 4));
      short8 va1 = *reinterpret_cast<const short8*>(Vb + rl * 64 + (((2 + h) ^ vkey) << 4));
      o[ct] = __builtin_amdgcn_mfma_f32_32x32x16_bf16(va0, u0.v, o[ct], 0, 0, 0);
      o[ct] = __builtin_amdgcn_mfma_f32_32x32x16_bf16(va1, u1.v, o[ct], 0, 0, 0);
    }
    __builtin_amdgcn_s_setprio(0);
    cur = (cur == 2) ? 0 : cur + 1;
    nxt = (nxt == 2) ? 0 : nxt + 1;
  }

  // ---- epilogue: unnormalized bf16 O partial + f32 lsum partial ----
  lsum += __shfl_xor(lsum, 32);
  unsigned short* op = opart + ((size_t)kvh * B_ + b) * (size_t)N_ * C_;
  const size_t rowoff = (size_t)qpos * C_ + ch * 128;
#pragma unroll
  for (int ct = 0; ct < 4; ++ct)
#pragma unroll
    for (int j = 0; j < 8; ++j) {
      const int c = ct * 32 + 2 * (j & 1) + 8 * (j >> 1) + 4 * h;
      unsigned wv = cvt_pk_bf16(o[ct][2 * j], o[ct][2 * j + 1]);
      *reinterpret_cast<unsigned*>(&op[rowoff + c]) = wv;
    }
  if (h == 0 && ch == 0)
    lsumpart[((size_t)kvh * B_ + b) * N_ + qpos] = lsum;
#undef STAGE_V
#undef STAGE_K
}

// ---------------- kernel 3: merge kv-split partials + residual ----------------
// out = x + (O0 + O1) / (l0 + l1).  8192 blocks x 256 thr x one f32x4 group.
__global__ __launch_bounds__(256) void merge_kernel(const unsigned short* __restrict__ opart,
                                                    const float* __restrict__ lsumpart,
                                                    const float* __restrict__ x,
                                                    float* __restrict__ out) {
  const int i4 = blockIdx.x * 256 + threadIdx.x;  // f32x4 group, total 2097152
  const int m = i4 >> 6;                          // row (64 groups per 256-c row)
  const float inv = 1.0f / (lsumpart[m] + lsumpart[B_ * N_ + m]);
  ushort4v a0 = *reinterpret_cast<const ushort4v*>(opart + (size_t)i4 * 4);
  ushort4v a1 = *reinterpret_cast<const ushort4v*>(opart + (size_t)B_ * N_ * C_ + (size_t)i4 * 4);
  f32x4 xr = *reinterpret_cast<const f32x4*>(x + (size_t)i4 * 4);
  f32x4 t;
  t[0] = xr[0] + (bf2f(a0[0]) + bf2f(a1[0])) * inv;
  t[1] = xr[1] + (bf2f(a0[1]) + bf2f(a1[1])) * inv;
  t[2] = xr[2] + (bf2f(a0[2]) + bf2f(a1[2])) * inv;
  t[3] = xr[3] + (bf2f(a0[3]) + bf2f(a1[3])) * inv;
  *reinterpret_cast<f32x4*>(out + (size_t)i4 * 4) = t;
}

extern "C" void kernel_launch(void* const* d_in, const int* in_sizes, int n_in,
                              void* d_out, int out_size, void* d_ws, size_t ws_size,
                              hipStream_t stream) {
  const float* x  = (const float*)d_in[0];
  const float* wq = (const float*)d_in[1];
  const float* wk = (const float*)d_in[2];
  const float* wv = (const float*)d_in[3];
  const float* wo = (const float*)d_in[4];
  float* out = (float*)d_out;
  char* ws = (char*)d_ws;
  unsigned short* wcomb = (unsigned short*)(ws + 0);         // 163840 B
  unsigned short* wv_b  = (unsigned short*)(ws + 163840);    // 131072 B
  unsigned short* woT_b = (unsigned short*)(ws + 294912);    // 131072 B
  unsigned short* q     = (unsigned short*)(ws + 425984);    // 2 MB
  unsigned short* k     = (unsigned short*)(ws + 2523136);   // 2 MB
  unsigned short* vwT   = (unsigned short*)(ws + 4620288);   // 16 MB
  unsigned short* opart = (unsigned short*)(ws + 21397504);  // 32 MB (2 parts)
  float*          lsump = (float*)(ws + 54951936);           // 256 KB (total ~55.2 MB)

  prep_kernel<<<576, 256, 0, stream>>>(wq, wk, wo, wv, wcomb, wv_b, woT_b);
  prep2_kernel<<<4, 256, 0, stream>>>(woT_b, wv_b, wcomb);
  qkv_kernel<<<512, 256, 0, stream>>>(x, wcomb, q, k, vwT);
  flash_kernel<<<1024, 256, 0, stream>>>(q, k, vwT, opart, lsump);
  merge_kernel<<<8192, 256, 0, stream>>>(opart, lsump, x, out);
}

// Round 10
// 154.476 us; speedup vs baseline: 2.3582x; 1.1219x over previous
//
#include <hip/hip_runtime.h>
#include <hip/hip_bf16.h>
#include <stdint.h>

typedef __attribute__((ext_vector_type(8))) short short8;
typedef __attribute__((ext_vector_type(8))) unsigned short ushort8;
typedef __attribute__((ext_vector_type(4))) unsigned short ushort4v;
typedef __attribute__((ext_vector_type(4))) float f32x4;
typedef __attribute__((ext_vector_type(16))) float f32x16;

#define B_ 8
#define N_ 4096
#define C_ 256
#define D_ 32
#define LOG2E 1.44269504088896f

__device__ inline unsigned short f2bf(float f) {
  union { float f; unsigned u; } v; v.f = f;
  unsigned r = v.u + 0x7fffu + ((v.u >> 16) & 1u);
  return (unsigned short)(r >> 16);
}
__device__ inline float bf2f(unsigned short u) {
  return __uint_as_float(((unsigned)u) << 16);
}
__device__ inline float exp2_fast(float x) {
  float r; asm("v_exp_f32 %0, %1" : "=v"(r) : "v"(x)); return r;
}
__device__ inline unsigned cvt_pk_bf16(float lo, float hi) {
  unsigned r; asm("v_cvt_pk_bf16_f32 %0, %1, %2" : "=v"(r) : "v"(lo), "v"(hi)); return r;
}
// a <- [a.l0-31 | b.l0-31], b <- [a.l32-63 | b.l32-63]
__device__ inline void permlane32_swap(unsigned& a, unsigned& b) {
  asm volatile("v_permlane32_swap_b32 %0, %1" : "+v"(a), "+v"(b));
}
__device__ inline void gll16(const unsigned short* src, void* lds) {
  __builtin_amdgcn_global_load_lds((const __attribute__((address_space(1))) void*)src,
                                   (__attribute__((address_space(3))) void*)lds, 16, 0, 0);
}

// ---------------- kernel 0a: weight casts ----------------
// wcomb[320][256]: rows 0-31 w_q^T*log2e | 32-63 w_k^T | rows 64-319 filled by prep2.
__global__ __launch_bounds__(256) void prep_kernel(const float* __restrict__ wq,
                                                   const float* __restrict__ wk,
                                                   const float* __restrict__ wo,
                                                   const float* __restrict__ wv,
                                                   unsigned short* __restrict__ wcomb,
                                                   unsigned short* __restrict__ wv_b,
                                                   unsigned short* __restrict__ woT_b) {
  int i = blockIdx.x * 256 + threadIdx.x;  // total 147456
  if (i < 16384) {
    int row = i >> 8, kk = i & 255;
    float v = (row < 32) ? wq[kk * 32 + row] * LOG2E : wk[kk * 32 + (row - 32)];
    wcomb[i] = f2bf(v);
  } else if (i < 81920) {
    int j = i - 16384;
    wv_b[j] = f2bf(wv[j]);
  } else {
    int j = i - 81920;  // woT_b[e2][e] = wo[e][e2]
    int e2 = j >> 8, e = j & 255;
    woT_b[j] = f2bf(wo[e * 256 + e2]);
  }
}

// ---------------- kernel 0b: Wvo^T = Wo^T . Wv^T  (256x256, K=256) ----------------
__global__ __launch_bounds__(256) void prep2_kernel(const unsigned short* __restrict__ woT_b,
                                                    const unsigned short* __restrict__ wv_b,
                                                    unsigned short* __restrict__ wcomb) {
  const int lane = threadIdx.x & 63, w = threadIdx.x >> 6;
  const int g = lane >> 4, li = lane & 15;
  const int m0 = blockIdx.x * 64 + w * 16;
  const unsigned short* arow = woT_b + (size_t)(m0 + li) * 256 + (g << 3);
  const unsigned short* brow = wv_b + (size_t)li * 256 + (g << 3);
  f32x4 acc[16] = {};
  for (int kk = 0; kk < 256; kk += 32) {
    short8 a = *reinterpret_cast<const short8*>(arow + kk);
#pragma unroll
    for (int ct = 0; ct < 16; ++ct) {
      short8 bb = *reinterpret_cast<const short8*>(brow + (size_t)ct * 16 * 256 + kk);
      acc[ct] = __builtin_amdgcn_mfma_f32_16x16x32_bf16(a, bb, acc[ct], 0, 0, 0);
    }
  }
#pragma unroll
  for (int ct = 0; ct < 16; ++ct)
#pragma unroll
    for (int r = 0; r < 4; ++r)
      wcomb[(size_t)(64 + m0 + (g << 2) + r) * 256 + ct * 16 + li] = f2bf(acc[ct][r]);
}

// ---------------- kernel 1: fused QKVW projection, W staged in LDS ----------------
__global__ __launch_bounds__(256, 2) void qkv_kernel(const float* __restrict__ x,
                                                     const unsigned short* __restrict__ wcomb,
                                                     unsigned short* __restrict__ q,
                                                     unsigned short* __restrict__ k,
                                                     unsigned short* __restrict__ vwT) {
  __shared__ __align__(16) char wls[61440];  // 3 x 20480
  const int tid = threadIdx.x;
  const int l = tid & 63, w = tid >> 6;
  const int bx = blockIdx.x;
  const int g = l >> 4, li = l & 15;
  const int mt = bx * 64 + w * 16;
  const float* xrow = x + (size_t)(mt + li) * 256 + (g << 3);

  // ---- issue all x loads first (oldest in vm queue) ----
  f32x4 xf[16];
#pragma unroll
  for (int s = 0; s < 8; ++s) {
    xf[2 * s]     = *reinterpret_cast<const f32x4*>(xrow + s * 32);
    xf[2 * s + 1] = *reinterpret_cast<const f32x4*>(xrow + s * 32 + 4);
  }
  __builtin_amdgcn_sched_barrier(0);  // keep x loads older than W stages

#define WSTAGE(BUF, S)                                                              \
  {                                                                                 \
    _Pragma("unroll") for (int t = 0; t < 5; ++t) {                                 \
      const int ct = w * 5 + t;                                                     \
      gll16(wcomb + (size_t)(ct * 16 + (l >> 2)) * 256 + (S) * 32 +                 \
                (((l & 3) ^ ((l >> 2) & 3)) << 3),                                  \
            wls + (BUF) * 20480 + ct * 1024);                                       \
    }                                                                               \
  }

  WSTAGE(0, 0)
  WSTAGE(1, 1)

  short8 xb[8];
#pragma unroll
  for (int s = 0; s < 8; ++s) {
    union { unsigned u[4]; short8 v; } A;
    A.u[0] = cvt_pk_bf16(xf[2 * s][0], xf[2 * s][1]);
    A.u[1] = cvt_pk_bf16(xf[2 * s][2], xf[2 * s][3]);
    A.u[2] = cvt_pk_bf16(xf[2 * s + 1][0], xf[2 * s + 1][1]);
    A.u[3] = cvt_pk_bf16(xf[2 * s + 1][2], xf[2 * s + 1][3]);
    xb[s] = A.v;
  }

  f32x4 acc[20] = {};
  const int roff = li * 64 + ((g ^ (li & 3)) << 4);

#define QSTEP(S, BUF, WN, DOSTAGE)                                                  \
  {                                                                                 \
    asm volatile("s_waitcnt vmcnt(" WN ")" ::: "memory");                           \
    __builtin_amdgcn_sched_barrier(0);                                              \
    __builtin_amdgcn_s_barrier();                                                   \
    if (DOSTAGE) WSTAGE(((S) + 2) % 3, (S) + 2)                                     \
    const char* Wb = wls + (BUF) * 20480;                                           \
    _Pragma("unroll") for (int ct = 0; ct < 20; ++ct) {                             \
      short8 bb = *reinterpret_cast<const short8*>(Wb + ct * 1024 + roff);          \
      acc[ct] = __builtin_amdgcn_mfma_f32_16x16x32_bf16(xb[(S)], bb, acc[ct], 0, 0, 0); \
    }                                                                               \
  }

  QSTEP(0, 0, "5", true)
  QSTEP(1, 1, "5", true)
  QSTEP(2, 2, "5", true)
  QSTEP(3, 0, "5", true)
  QSTEP(4, 1, "5", true)
  QSTEP(5, 2, "5", true)
  QSTEP(6, 0, "5", false)
  QSTEP(7, 1, "0", false)

  const int bb_ = bx >> 6;
  const int nloc = (bx & 63) * 64 + w * 16 + (g << 2);
#pragma unroll
  for (int ct = 0; ct < 4; ++ct) {
    int col = ct * 16 + li;
    unsigned short* dst = (ct < 2) ? q : k;
    int cc = (ct < 2) ? col : col - 32;
#pragma unroll
    for (int r = 0; r < 4; ++r)
      dst[((size_t)bb_ * N_ + nloc + r) * D_ + cc] = f2bf(acc[ct][r]);
  }
#pragma unroll
  for (int ct = 4; ct < 20; ++ct) {
    int vcol = (ct - 4) * 16 + li;
    union { unsigned u[2]; ushort4v v; } P;
    P.u[0] = cvt_pk_bf16(acc[ct][0], acc[ct][1]);
    P.u[1] = cvt_pk_bf16(acc[ct][2], acc[ct][3]);
    *reinterpret_cast<ushort4v*>(&vwT[((size_t)bb_ * C_ + vcol) * N_ + nloc]) = P.v;
  }
#undef QSTEP
#undef WSTAGE
}

// ---------------- kernel 2: flash attention (64q waves + counted-vmcnt staging) ----
// grid 512 x 256. blk: b = blk&7 (XCD pin), kvh = (blk>>3)&1, qt = blk>>4 (0..31).
// Block tile 128q x 256c over 2048 kv (64 chunks of 32). 4 waves: qg = w>>1, ch = w&1;
// wave = 64q x 128c (two 32q subtiles qt2 -> each V-frag read feeds 2 PV MFMAs).
// V triple-buffered 3x16KB staged 2-ahead; K double-buffered 2x2KB staged 1-ahead
// (K issued BEFORE V so the steady-state wait is uniform vmcnt(4); drained to 0
// only at the last chunk). One s_barrier per chunk. P in registers (swapped
// S^T=K.Q^T, fixed m=0, q pre-scaled log2e); output projection folded into vwT.
// Writes unnormalized bf16 O partial + f32 lsum partial per kvh; merge_kernel sums.
__global__ __launch_bounds__(256, 2) void flash_kernel(const unsigned short* __restrict__ q,
                                                       const unsigned short* __restrict__ k,
                                                       const unsigned short* __restrict__ vwT,
                                                       unsigned short* __restrict__ opart,
                                                       float* __restrict__ lsumpart) {
  __shared__ __align__(16) char smem[53248];  // V 3x16384 @0 | K 2x2048 @49152
  const int tid = threadIdx.x;
  const int l = tid & 63, w_ = tid >> 6;
  const int qg = w_ >> 1, ch = w_ & 1;
  const int blk = blockIdx.x;
  const int b = blk & 7;
  const int kvh = (blk >> 3) & 1;
  const int qt = blk >> 4;  // 0..31
  const int h = l >> 5, l31 = l & 31;

  const unsigned short* kb_ = k + (size_t)b * N_ * D_;
  const unsigned short* vb_ = vwT + (size_t)b * C_ * N_;

  // Q B-frags qb[qt2][ks]: col q = l31, k-dim = ks*16 + 8h + j
  const int qposb = qt * 128 + qg * 64;  // + qt2*32 + l31
  short8 qb[2][2];
#pragma unroll
  for (int qt2 = 0; qt2 < 2; ++qt2) {
    const size_t qoff = ((size_t)b * N_ + qposb + qt2 * 32 + l31) * D_ + h * 8;
    qb[qt2][0] = *reinterpret_cast<const short8*>(q + qoff);
    qb[qt2][1] = *reinterpret_cast<const short8*>(q + qoff + 16);
  }
  asm volatile("s_waitcnt vmcnt(0)" ::: "memory");  // clean vm counter before staging

  const int stg_row = l >> 2;
  const int stg_bk = ((l & 3) ^ ((l >> 3) & 3)) << 3;  // elems
  const int kvbase = kvh * 2048;

  // wave stages V rows w_*64..+63 (4 gll16); waves 0,1 stage 16 K rows each (1 gll16).
#define STAGE_V(BUF, KV0)                                                         \
  {                                                                               \
    char* vd = smem + (BUF) * 16384 + w_ * 4096;                                  \
    _Pragma("unroll") for (int t = 0; t < 4; ++t)                                 \
        gll16(vb_ + (size_t)(w_ * 64 + t * 16 + stg_row) * N_ + (KV0) + stg_bk,   \
              vd + t * 1024);                                                     \
  }
#define STAGE_K(BUF, KV0)                                                         \
  {                                                                               \
    if (w_ < 2)                                                                   \
      gll16(kb_ + (size_t)((KV0) + w_ * 16 + stg_row) * D_ + stg_bk,              \
            smem + 49152 + (BUF) * 2048 + w_ * 1024);                             \
  }

  f32x16 o[4][2] = {};  // [ct][qt2]: O^T (32c x 32q), c = ch*128 + ct*32
  float lsum[2] = {0.f, 0.f};
  const f32x16 z16 = {};

  // prologue: V(0), K(0), V(1)  -> first-iter vmcnt(4) drains V(0)+K(0)
  STAGE_V(0, kvbase)
  STAGE_K(0, kvbase)
  STAGE_V(1, kvbase + 32)

  int cur = 0, nxt = 2;
  for (int i = 0; i < 64; ++i) {
    if (i < 63) { asm volatile("s_waitcnt vmcnt(4)" ::: "memory"); }
    else        { asm volatile("s_waitcnt vmcnt(0)" ::: "memory"); }
    __builtin_amdgcn_sched_barrier(0);
    __builtin_amdgcn_s_barrier();  // chunk i landed; all waves done with prev reads
    if (i < 63) STAGE_K((i + 1) & 1, kvbase + (i + 1) * 32)
    if (i < 62) STAGE_V(nxt, kvbase + (i + 2) * 32)
    const char* Vb = smem + cur * 16384;
    const char* Kb = smem + 49152 + (i & 1) * 2048;
    // ---- S^T[32kv][32q] = K . Q^T per qt2; exp; pack to PV B-frags ----
    const int kkey = (l31 >> 1) & 3;
    short8 ka0 = *reinterpret_cast<const short8*>(Kb + l31 * 64 + (((0 + h) ^ kkey) << 4));
    short8 ka1 = *reinterpret_cast<const short8*>(Kb + l31 * 64 + (((2 + h) ^ kkey) << 4));
    short8 pf[2][2];
#pragma unroll
    for (int qt2 = 0; qt2 < 2; ++qt2) {
      f32x16 s = __builtin_amdgcn_mfma_f32_32x32x16_bf16(ka0, qb[qt2][0], z16, 0, 0, 0);
      s = __builtin_amdgcn_mfma_f32_32x32x16_bf16(ka1, qb[qt2][1], s, 0, 0, 0);
      float p[16];
#pragma unroll
      for (int r = 0; r < 16; ++r) p[r] = exp2_fast(s[r]);
      lsum[qt2] += (((p[0] + p[1]) + (p[2] + p[3])) + ((p[4] + p[5]) + (p[6] + p[7]))) +
                   (((p[8] + p[9]) + (p[10] + p[11])) + ((p[12] + p[13]) + (p[14] + p[15])));
      unsigned x0 = cvt_pk_bf16(p[0], p[1]),   y0 = cvt_pk_bf16(p[4], p[5]);
      unsigned x1 = cvt_pk_bf16(p[2], p[3]),   y1 = cvt_pk_bf16(p[6], p[7]);
      unsigned x2 = cvt_pk_bf16(p[8], p[9]),   y2 = cvt_pk_bf16(p[12], p[13]);
      unsigned x3 = cvt_pk_bf16(p[10], p[11]), y3 = cvt_pk_bf16(p[14], p[15]);
      permlane32_swap(x0, y0); permlane32_swap(x1, y1);
      permlane32_swap(x2, y2); permlane32_swap(x3, y3);
      union U { unsigned u[4]; short8 v; };
      U u0; u0.u[0] = x0; u0.u[1] = x1; u0.u[2] = y0; u0.u[3] = y1;  // kv 0-15
      U u1; u1.u[0] = x2; u1.u[1] = x3; u1.u[2] = y2; u1.u[3] = y3;  // kv 16-31
      pf[qt2][0] = u0.v; pf[qt2][1] = u1.v;
    }
    // ---- PV: O^T[c][q] += V^T . P^T (each va read feeds both qt2) ----
    __builtin_amdgcn_s_setprio(1);
#pragma unroll
    for (int ct = 0; ct < 4; ++ct) {
      const int rl = ch * 128 + ct * 32 + l31;
      const int vkey = (rl >> 1) & 3;
      short8 va0 = *reinterpret_cast<const short8*>(Vb + rl * 64 + (((0 + h) ^ vkey) << 4));
      short8 va1 = *reinterpret_cast<const short8*>(Vb + rl * 64 + (((2 + h) ^ vkey) << 4));
      o[ct][0] = __builtin_amdgcn_mfma_f32_32x32x16_bf16(va0, pf[0][0], o[ct][0], 0, 0, 0);
      o[ct][0] = __builtin_amdgcn_mfma_f32_32x32x16_bf16(va1, pf[0][1], o[ct][0], 0, 0, 0);
      o[ct][1] = __builtin_amdgcn_mfma_f32_32x32x16_bf16(va0, pf[1][0], o[ct][1], 0, 0, 0);
      o[ct][1] = __builtin_amdgcn_mfma_f32_32x32x16_bf16(va1, pf[1][1], o[ct][1], 0, 0, 0);
    }
    __builtin_amdgcn_s_setprio(0);
    cur = (cur == 2) ? 0 : cur + 1;
    nxt = (nxt == 2) ? 0 : nxt + 1;
  }

  // ---- epilogue: unnormalized bf16 O partial + f32 lsum partial ----
  lsum[0] += __shfl_xor(lsum[0], 32);
  lsum[1] += __shfl_xor(lsum[1], 32);
  unsigned short* op = opart + ((size_t)kvh * B_ + b) * (size_t)N_ * C_;
#pragma unroll
  for (int qt2 = 0; qt2 < 2; ++qt2) {
    const size_t rowoff = (size_t)(qposb + qt2 * 32 + l31) * C_ + ch * 128;
#pragma unroll
    for (int ct = 0; ct < 4; ++ct)
#pragma unroll
      for (int j = 0; j < 8; ++j) {
        const int c = ct * 32 + 2 * (j & 1) + 8 * (j >> 1) + 4 * h;
        unsigned wv = cvt_pk_bf16(o[ct][qt2][2 * j], o[ct][qt2][2 * j + 1]);
        *reinterpret_cast<unsigned*>(&op[rowoff + c]) = wv;
      }
  }
  if (h == 0 && ch == 0) {
    float* lp = lsumpart + ((size_t)kvh * B_ + b) * N_ + qposb;
    lp[l31] = lsum[0];
    lp[32 + l31] = lsum[1];
  }
#undef STAGE_V
#undef STAGE_K
}

// ---------------- kernel 3: merge kv-split partials + residual ----------------
// out = x + (O0 + O1) / (l0 + l1).  8192 blocks x 256 thr x one f32x4 group.
__global__ __launch_bounds__(256) void merge_kernel(const unsigned short* __restrict__ opart,
                                                    const float* __restrict__ lsumpart,
                                                    const float* __restrict__ x,
                                                    float* __restrict__ out) {
  const int i4 = blockIdx.x * 256 + threadIdx.x;  // f32x4 group, total 2097152
  const int m = i4 >> 6;                          // row (64 groups per 256-c row)
  const float inv = 1.0f / (lsumpart[m] + lsumpart[B_ * N_ + m]);
  ushort4v a0 = *reinterpret_cast<const ushort4v*>(opart + (size_t)i4 * 4);
  ushort4v a1 = *reinterpret_cast<const ushort4v*>(opart + (size_t)B_ * N_ * C_ + (size_t)i4 * 4);
  f32x4 xr = *reinterpret_cast<const f32x4*>(x + (size_t)i4 * 4);
  f32x4 t;
  t[0] = xr[0] + (bf2f(a0[0]) + bf2f(a1[0])) * inv;
  t[1] = xr[1] + (bf2f(a0[1]) + bf2f(a1[1])) * inv;
  t[2] = xr[2] + (bf2f(a0[2]) + bf2f(a1[2])) * inv;
  t[3] = xr[3] + (bf2f(a0[3]) + bf2f(a1[3])) * inv;
  *reinterpret_cast<f32x4*>(out + (size_t)i4 * 4) = t;
}

extern "C" void kernel_launch(void* const* d_in, const int* in_sizes, int n_in,
                              void* d_out, int out_size, void* d_ws, size_t ws_size,
                              hipStream_t stream) {
  const float* x  = (const float*)d_in[0];
  const float* wq = (const float*)d_in[1];
  const float* wk = (const float*)d_in[2];
  const float* wv = (const float*)d_in[3];
  const float* wo = (const float*)d_in[4];
  float* out = (float*)d_out;
  char* ws = (char*)d_ws;
  unsigned short* wcomb = (unsigned short*)(ws + 0);         // 163840 B
  unsigned short* wv_b  = (unsigned short*)(ws + 163840);    // 131072 B
  unsigned short* woT_b = (unsigned short*)(ws + 294912);    // 131072 B
  unsigned short* q     = (unsigned short*)(ws + 425984);    // 2 MB
  unsigned short* k     = (unsigned short*)(ws + 2523136);   // 2 MB
  unsigned short* vwT   = (unsigned short*)(ws + 4620288);   // 16 MB
  unsigned short* opart = (unsigned short*)(ws + 21397504);  // 32 MB (2 parts)
  float*          lsump = (float*)(ws + 54951936);           // 256 KB (total ~55.2 MB)

  prep_kernel<<<576, 256, 0, stream>>>(wq, wk, wo, wv, wcomb, wv_b, woT_b);
  prep2_kernel<<<4, 256, 0, stream>>>(woT_b, wv_b, wcomb);
  qkv_kernel<<<512, 256, 0, stream>>>(x, wcomb, q, k, vwT);
  flash_kernel<<<512, 256, 0, stream>>>(q, k, vwT, opart, lsump);
  merge_kernel<<<8192, 256, 0, stream>>>(opart, lsump, x, out);
}